// Round 6
// baseline (269.330 us; speedup 1.0000x reference)
//
#include <hip/hip_runtime.h>

#define N_USERS 100000
#define N_ITEMS 50000
#define EMB 64
#define N_EDGES 1000000

// ---- bucketed CSR build parameters ----
#define SH_U 9                 // 512 users per bucket
#define SH_I 8                 // 256 items per bucket
#define NBUK 196               // ceil(100000/512) == ceil(50000/256) == 196
#define B1 256                 // pass-A blocks
#define CHUNK ((N_EDGES + B1 - 1) / B1)   // 3907
#define HN (2 * NBUK * B1)     // 100352 histogram entries (logical, bucket-major)
#define HTILE 4096
#define HTILES ((HN + HTILE - 1) / HTILE) // 25

typedef unsigned short u16;
typedef u16 us8 __attribute__((ext_vector_type(8)));
typedef u16 us4 __attribute__((ext_vector_type(4)));
typedef float f4 __attribute__((ext_vector_type(4)));

static __device__ __forceinline__ float bf2f(u16 h) {
    return __uint_as_float(((unsigned)h) << 16);
}
static __device__ __forceinline__ u16 f2bf(float f) {
    unsigned u = __float_as_uint(f);
    return (u16)((u + 0x7FFFu + ((u >> 16) & 1u)) >> 16);
}

// logical hist index L (= (side*NBUK + b)*B1 + blk) -> physical (block-major)
static __device__ __forceinline__ int hphys(int L) {
    int sb = L >> 8;          // B1 == 256
    int blk = L & 255;
    return blk * (2 * NBUK) + sb;
}

// f32 -> bf16 table conversion, 4 elems/thread
__global__ void conv_kernel(const float* __restrict__ a, u16* __restrict__ b, int n4) {
    int t = blockIdx.x * blockDim.x + threadIdx.x;
    if (t >= n4) return;
    f4 v = ((const f4*)a)[t];
    us4 w;
    w.x = f2bf(v.x); w.y = f2bf(v.y); w.z = f2bf(v.z); w.w = f2bf(v.w);
    ((us4*)b)[t] = w;
}

// ---- Pass A1: per-block bucket histograms ----
__global__ void histA_kernel(const int* __restrict__ uidx, const int* __restrict__ iidx,
                             int* __restrict__ H) {
    __shared__ int hu[NBUK];
    __shared__ int hi[NBUK];
    int tid = threadIdx.x, blk = blockIdx.x;
    for (int b = tid; b < NBUK; b += 256) { hu[b] = 0; hi[b] = 0; }
    __syncthreads();
    int e0 = blk * CHUNK;
    int e1 = e0 + CHUNK; if (e1 > N_EDGES) e1 = N_EDGES;
    for (int e = e0 + tid; e < e1; e += 256) {
        atomicAdd(&hu[uidx[e] >> SH_U], 1);
        atomicAdd(&hi[iidx[e] >> SH_I], 1);
    }
    __syncthreads();
    int* Hb = H + blk * (2 * NBUK);
    for (int b = tid; b < NBUK; b += 256) {
        Hb[b] = hu[b];
        Hb[NBUK + b] = hi[b];
    }
}

// ---- Pass A2: 2-level exclusive scan over logical order ----
__global__ void hscan_tile_kernel(const int* __restrict__ H, int* __restrict__ part) {
    int t = blockIdx.x, tid = threadIdx.x;
    int base = t * HTILE;
    int s = 0;
    for (int i = tid; i < HTILE; i += 256) {
        int L = base + i;
        if (L < HN) s += H[hphys(L)];
    }
    #pragma unroll
    for (int o = 32; o > 0; o >>= 1) s += __shfl_xor(s, o);
    __shared__ int wsum[4];
    if ((tid & 63) == 0) wsum[tid >> 6] = s;
    __syncthreads();
    if (tid == 0) part[t] = wsum[0] + wsum[1] + wsum[2] + wsum[3];
}

__global__ void hscan_write_kernel(const int* __restrict__ H, const int* __restrict__ part,
                                   int* __restrict__ HB) {
    int t = blockIdx.x, tid = threadIdx.x;
    int base = t * HTILE;

    __shared__ int lds[HTILE];
    for (int i = tid; i < HTILE; i += 256) {
        int L = base + i;
        lds[i] = (L < HN) ? H[hphys(L)] : 0;
    }
    __syncthreads();

    int pbase = 0;
    for (int p = 0; p < t; ++p) pbase += part[p];

    int tsum = 0;
    #pragma unroll
    for (int i = 0; i < 16; ++i) tsum += lds[tid * 16 + i];

    int lane = tid & 63, wid = tid >> 6;
    int x = tsum;
    #pragma unroll
    for (int o = 1; o < 64; o <<= 1) {
        int tt = __shfl_up(x, o);
        if (lane >= o) x += tt;
    }
    __shared__ int wsum[4];
    if (lane == 63) wsum[wid] = x;
    __syncthreads();
    int wbase = 0;
    for (int w = 0; w < wid; ++w) wbase += wsum[w];

    int run = pbase + wbase + x - tsum;
    #pragma unroll
    for (int i = 0; i < 16; ++i) {
        int L = base + tid * 16 + i;
        if (L < HN) HB[L] = run;
        run += lds[tid * 16 + i];
    }
}

// ---- Pass A3: scatter edges into bucket-segmented record array ----
// user record: (u&511)<<16 | item ; item record: (i&255)<<17 | user
__global__ void scatterA_kernel(const int* __restrict__ uidx, const int* __restrict__ iidx,
                                const int* __restrict__ HB, int* __restrict__ rec) {
    __shared__ int cu[NBUK];
    __shared__ int ci[NBUK];
    int tid = threadIdx.x, blk = blockIdx.x;
    for (int sb = tid; sb < 2 * NBUK; sb += 256) {
        int v = HB[sb * B1 + blk];
        if (sb < NBUK) cu[sb] = v; else ci[sb - NBUK] = v;
    }
    __syncthreads();
    int e0 = blk * CHUNK;
    int e1 = e0 + CHUNK; if (e1 > N_EDGES) e1 = N_EDGES;
    for (int e = e0 + tid; e < e1; e += 256) {
        int u = uidx[e];
        int i = iidx[e];
        int pu = atomicAdd(&cu[u >> SH_U], 1);
        rec[pu] = ((u & 511) << 16) | i;
        int pi = atomicAdd(&ci[i >> SH_I], 1);
        rec[pi] = ((i & 255) << 17) | u;
    }
}

// ---- Pass B: per-bucket CSR finalize (offs + list of BYTE offsets) ----
__global__ void bucketB_kernel(const int* __restrict__ HB, const int* __restrict__ rec,
                               int* __restrict__ offs_u, int* __restrict__ offs_i,
                               int* __restrict__ list) {
    int sb = blockIdx.x, tid = threadIdx.x;
    int side = (sb >= NBUK) ? 1 : 0;
    int b = sb - side * NBUK;
    int start = HB[sb * B1];
    int end = (sb == 2 * NBUK - 1) ? 2 * N_EDGES : HB[(sb + 1) * B1];
    int shift = side ? 17 : 16;
    int mask  = side ? 0x1FFFF : 0xFFFF;
    int nd    = side ? 256 : 512;
    int dbase = side ? (b << SH_I) : (b << SH_U);
    int n     = side ? N_ITEMS : N_USERS;
    int rel   = start - side * N_EDGES;
    int* offs = side ? offs_i : offs_u;

    __shared__ int cnt[512];
    __shared__ int scn[512];
    __shared__ int wsum[4];
    if (tid < 256) { cnt[tid] = 0; cnt[256 + tid] = 0; }
    __syncthreads();

    for (int r = start + tid; r < end; r += 256)
        atomicAdd(&cnt[rec[r] >> shift], 1);
    __syncthreads();

    int a0 = cnt[2 * tid], a1 = cnt[2 * tid + 1];
    int s = a0 + a1;
    int lane = tid & 63, wid = tid >> 6;
    int x = s;
    #pragma unroll
    for (int o = 1; o < 64; o <<= 1) {
        int tt = __shfl_up(x, o);
        if (lane >= o) x += tt;
    }
    if (lane == 63) wsum[wid] = x;
    __syncthreads();
    int wbase = 0;
    for (int w = 0; w < wid; ++w) wbase += wsum[w];
    int excl = wbase + x - s;
    scn[2 * tid] = excl;
    scn[2 * tid + 1] = excl + a0;
    __syncthreads();

    for (int dl = tid; dl < nd; dl += 256) {
        int dg = dbase + dl;
        if (dg < n) offs[dg] = rel + scn[dl];
    }
    if (b == NBUK - 1 && tid == 0) offs[n] = (end - side * N_EDGES);
    __syncthreads();

    for (int r = start + tid; r < end; r += 256) {
        int v = rec[r];
        int dl = v >> shift;
        int pos = atomicAdd(&scn[dl], 1);
        list[start + pos] = (v & mask) << 7;   // byte offset of source row (id*128)
    }
}

// ---- Fused per-hop gather + segment-sum + L2-norm + out accumulate ----
// One wave per destination row. Lane (grp,sub): grp picks the edge slot within
// a batch of 8, sub picks the 16B chunk of the 128B bf16 row. No shfl in the
// inner loop: lane loads its own index (32B coalesced per wave).
__global__ void gather_norm_v2(const u16* __restrict__ srcU,
                               const u16* __restrict__ srcI,
                               const int* __restrict__ offs_u, const int* __restrict__ list_u,
                               const int* __restrict__ offs_i, const int* __restrict__ list_i,
                               u16* __restrict__ aggU, u16* __restrict__ aggI,
                               float* __restrict__ outU, float* __restrict__ outI,
                               const float* __restrict__ initU, const float* __restrict__ initI,
                               int first) {
    int t = blockIdx.x * blockDim.x + threadIdx.x;
    int r = t >> 6;
    int lane = t & 63;
    const u16* src; const int* offs; const int* list;
    u16* agg; float* out; const float* init; int rr;
    if (r < N_USERS) {
        src = srcU; offs = offs_u; list = list_u;
        agg = aggU; out = outU; init = initU; rr = r;
    } else {
        src = srcI; offs = offs_i; list = list_i;
        agg = aggI; out = outI; init = initI; rr = r - N_USERS;
    }
    int beg = offs[rr];
    int end = offs[rr + 1];
    int deg = end - beg;
    int grp = lane >> 3, sub = lane & 7;

    const char* srcB = (const char*)src;
    unsigned suboff = (unsigned)(sub << 4);       // sub*16 bytes
    const int* lp = list + beg + grp;

    float acc[8] = {0.f, 0.f, 0.f, 0.f, 0.f, 0.f, 0.f, 0.f};

    int nt = (deg + 7) >> 3;
    #pragma unroll 2
    for (int it = 0; it < nt; ++it) {
        if ((it << 3) + grp < deg) {
            unsigned jb = (unsigned)lp[it << 3];  // pre-scaled byte offset
            us8 v = *(const us8*)(srcB + (jb + suboff));
            #pragma unroll
            for (int i = 0; i < 8; ++i) acc[i] += bf2f(v[i]);
        }
    }

    // fold the 8 edge-groups (butterfly -> every lane has all 8 column totals)
    #pragma unroll
    for (int o = 8; o < 64; o <<= 1) {
        #pragma unroll
        for (int i = 0; i < 8; ++i) acc[i] += __shfl_xor(acc[i], o);
    }

    // ||row||^2: each lane sums its 8 dims (sub*8..sub*8+7), reduce over sub
    float q = 0.f;
    #pragma unroll
    for (int i = 0; i < 8; ++i) q += acc[i] * acc[i];
    q += __shfl_xor(q, 1);
    q += __shfl_xor(q, 2);
    q += __shfl_xor(q, 4);
    float inv = 1.f / fmaxf(sqrtf(q), 1e-12f);

    // distributed epilogue: lane handles dim d = sub*8 + grp (select acc[grp])
    bool b0 = (grp & 1) != 0, b1 = (grp & 2) != 0, b2 = (grp & 4) != 0;
    float t0 = b0 ? acc[1] : acc[0];
    float t1 = b0 ? acc[3] : acc[2];
    float t2 = b0 ? acc[5] : acc[4];
    float t3 = b0 ? acc[7] : acc[6];
    float u0 = b1 ? t1 : t0;
    float u1 = b1 ? t3 : t2;
    float sel = b2 ? u1 : u0;
    float y = sel * inv;

    int d = (sub << 3) + grp;
    size_t off = (size_t)rr * EMB + d;
    agg[off] = f2bf(y);
    float o = first ? init[off] : out[off];
    out[off] = o + y;
}

extern "C" void kernel_launch(void* const* d_in, const int* in_sizes, int n_in,
                              void* d_out, int out_size, void* d_ws, size_t ws_size,
                              hipStream_t stream) {
    const float* user_emb = (const float*)d_in[0];
    const float* item_emb = (const float*)d_in[1];
    const int*   uidx     = (const int*)d_in[2];
    const int*   iidx     = (const int*)d_in[3];

    float* out      = (float*)d_out;
    float* out_item = out;                           // [N_ITEMS, 64]
    float* out_user = out + (size_t)N_ITEMS * EMB;   // [N_USERS, 64]

    // workspace layout: bf16 tables first (16B-aligned), then int arrays
    u16* ws16    = (u16*)d_ws;
    u16* ua_bf   = ws16;
    u16* ub_bf   = ua_bf + (size_t)N_USERS * EMB;
    u16* ia_bf   = ub_bf + (size_t)N_USERS * EMB;
    u16* ib_bf   = ia_bf + (size_t)N_ITEMS * EMB;
    u16* uemb_bf = ib_bf + (size_t)N_ITEMS * EMB;
    u16* iemb_bf = uemb_bf + (size_t)N_USERS * EMB;
    int* rec     = (int*)(iemb_bf + (size_t)N_ITEMS * EMB);
    int* list    = rec + 2 * N_EDGES;
    int* list_u  = list;
    int* list_i  = list + N_EDGES;
    int* offs_u  = list + 2 * N_EDGES;
    int* offs_i  = offs_u + (N_USERS + 1);
    int* H       = offs_i + (N_ITEMS + 1);
    int* HB      = H + HN;
    int* part    = HB + HN;

    // bf16 copies of the embeddings (hop-0 gather sources)
    conv_kernel<<<(N_USERS * EMB / 4 + 255) / 256, 256, 0, stream>>>(user_emb, uemb_bf, N_USERS * EMB / 4);
    conv_kernel<<<(N_ITEMS * EMB / 4 + 255) / 256, 256, 0, stream>>>(item_emb, iemb_bf, N_ITEMS * EMB / 4);

    // bucketed CSR build
    histA_kernel<<<B1, 256, 0, stream>>>(uidx, iidx, H);
    hscan_tile_kernel<<<HTILES, 256, 0, stream>>>(H, part);
    hscan_write_kernel<<<HTILES, 256, 0, stream>>>(H, part, HB);
    scatterA_kernel<<<B1, 256, 0, stream>>>(uidx, iidx, HB, rec);
    bucketB_kernel<<<2 * NBUK, 256, 0, stream>>>(HB, rec, offs_u, offs_i, list);

    // 3 hops
    const u16* us_bf = uemb_bf;
    const u16* is_bf = iemb_bf;
    const int nblocks = ((N_USERS + N_ITEMS) * EMB) / 256;  // 37500

    for (int hop = 0; hop < 3; ++hop) {
        u16* ud = (hop & 1) ? ub_bf : ua_bf;
        u16* id = (hop & 1) ? ib_bf : ia_bf;

        gather_norm_v2<<<nblocks, 256, 0, stream>>>(
            is_bf, us_bf, offs_u, list_u, offs_i, list_i,
            ud, id, out_user, out_item, user_emb, item_emb, hop == 0);

        us_bf = ud;
        is_bf = id;
    }
}

// Round 7
// 258.527 us; speedup vs baseline: 1.0418x; 1.0418x over previous
//
#include <hip/hip_runtime.h>

#define N_USERS 100000
#define N_ITEMS 50000
#define NROWS (N_USERS + N_ITEMS)
#define EMB 64
#define N_EDGES 1000000

// ---- bucketed CSR build parameters ----
#define SH_U 9                 // 512 users per bucket
#define SH_I 8                 // 256 items per bucket
#define NBUK 196
#define B1 256
#define CHUNK ((N_EDGES + B1 - 1) / B1)   // 3907
#define HN (2 * NBUK * B1)
#define HTILE 4096
#define HTILES ((HN + HTILE - 1) / HTILE) // 25
#define DBINS 64

typedef unsigned short u16;
typedef u16 us8 __attribute__((ext_vector_type(8)));
typedef u16 us4 __attribute__((ext_vector_type(4)));
typedef float f4 __attribute__((ext_vector_type(4)));

static __device__ __forceinline__ float bf2f(u16 h) {
    return __uint_as_float(((unsigned)h) << 16);
}
static __device__ __forceinline__ u16 f2bf(float f) {
    unsigned u = __float_as_uint(f);
    return (u16)((u + 0x7FFFu + ((u >> 16) & 1u)) >> 16);
}

static __device__ __forceinline__ int hphys(int L) {
    int sb = L >> 8;
    int blk = L & 255;
    return blk * (2 * NBUK) + sb;
}

__global__ void conv_kernel(const float* __restrict__ a, u16* __restrict__ b, int n4) {
    int t = blockIdx.x * blockDim.x + threadIdx.x;
    if (t >= n4) return;
    f4 v = ((const f4*)a)[t];
    us4 w;
    w.x = f2bf(v.x); w.y = f2bf(v.y); w.z = f2bf(v.z); w.w = f2bf(v.w);
    ((us4*)b)[t] = w;
}

// ---- Pass A1: per-block bucket histograms ----
__global__ void histA_kernel(const int* __restrict__ uidx, const int* __restrict__ iidx,
                             int* __restrict__ H) {
    __shared__ int hu[NBUK];
    __shared__ int hi[NBUK];
    int tid = threadIdx.x, blk = blockIdx.x;
    for (int b = tid; b < NBUK; b += 256) { hu[b] = 0; hi[b] = 0; }
    __syncthreads();
    int e0 = blk * CHUNK;
    int e1 = e0 + CHUNK; if (e1 > N_EDGES) e1 = N_EDGES;
    for (int e = e0 + tid; e < e1; e += 256) {
        atomicAdd(&hu[uidx[e] >> SH_U], 1);
        atomicAdd(&hi[iidx[e] >> SH_I], 1);
    }
    __syncthreads();
    int* Hb = H + blk * (2 * NBUK);
    for (int b = tid; b < NBUK; b += 256) {
        Hb[b] = hu[b];
        Hb[NBUK + b] = hi[b];
    }
}

// ---- Pass A2: 2-level exclusive scan over logical order ----
__global__ void hscan_tile_kernel(const int* __restrict__ H, int* __restrict__ part) {
    int t = blockIdx.x, tid = threadIdx.x;
    int base = t * HTILE;
    int s = 0;
    for (int i = tid; i < HTILE; i += 256) {
        int L = base + i;
        if (L < HN) s += H[hphys(L)];
    }
    #pragma unroll
    for (int o = 32; o > 0; o >>= 1) s += __shfl_xor(s, o);
    __shared__ int wsum[4];
    if ((tid & 63) == 0) wsum[tid >> 6] = s;
    __syncthreads();
    if (tid == 0) part[t] = wsum[0] + wsum[1] + wsum[2] + wsum[3];
}

__global__ void hscan_write_kernel(const int* __restrict__ H, const int* __restrict__ part,
                                   int* __restrict__ HB) {
    int t = blockIdx.x, tid = threadIdx.x;
    int base = t * HTILE;

    __shared__ int lds[HTILE];
    for (int i = tid; i < HTILE; i += 256) {
        int L = base + i;
        lds[i] = (L < HN) ? H[hphys(L)] : 0;
    }
    __syncthreads();

    int pbase = 0;
    for (int p = 0; p < t; ++p) pbase += part[p];

    int tsum = 0;
    #pragma unroll
    for (int i = 0; i < 16; ++i) tsum += lds[tid * 16 + i];

    int lane = tid & 63, wid = tid >> 6;
    int x = tsum;
    #pragma unroll
    for (int o = 1; o < 64; o <<= 1) {
        int tt = __shfl_up(x, o);
        if (lane >= o) x += tt;
    }
    __shared__ int wsum[4];
    if (lane == 63) wsum[wid] = x;
    __syncthreads();
    int wbase = 0;
    for (int w = 0; w < wid; ++w) wbase += wsum[w];

    int run = pbase + wbase + x - tsum;
    #pragma unroll
    for (int i = 0; i < 16; ++i) {
        int L = base + tid * 16 + i;
        if (L < HN) HB[L] = run;
        run += lds[tid * 16 + i];
    }
}

// ---- Pass A3: scatter edges into bucket-segmented record array ----
__global__ void scatterA_kernel(const int* __restrict__ uidx, const int* __restrict__ iidx,
                                const int* __restrict__ HB, int* __restrict__ rec) {
    __shared__ int cu[NBUK];
    __shared__ int ci[NBUK];
    int tid = threadIdx.x, blk = blockIdx.x;
    for (int sb = tid; sb < 2 * NBUK; sb += 256) {
        int v = HB[sb * B1 + blk];
        if (sb < NBUK) cu[sb] = v; else ci[sb - NBUK] = v;
    }
    __syncthreads();
    int e0 = blk * CHUNK;
    int e1 = e0 + CHUNK; if (e1 > N_EDGES) e1 = N_EDGES;
    for (int e = e0 + tid; e < e1; e += 256) {
        int u = uidx[e];
        int i = iidx[e];
        int pu = atomicAdd(&cu[u >> SH_U], 1);
        rec[pu] = ((u & 511) << 16) | i;
        int pi = atomicAdd(&ci[i >> SH_I], 1);
        rec[pi] = ((i & 255) << 17) | u;
    }
}

// ---- Pass B: per-bucket CSR finalize (offs + list of BYTE offsets) ----
__global__ void bucketB_kernel(const int* __restrict__ HB, const int* __restrict__ rec,
                               int* __restrict__ offs_u, int* __restrict__ offs_i,
                               int* __restrict__ list) {
    int sb = blockIdx.x, tid = threadIdx.x;
    int side = (sb >= NBUK) ? 1 : 0;
    int b = sb - side * NBUK;
    int start = HB[sb * B1];
    int end = (sb == 2 * NBUK - 1) ? 2 * N_EDGES : HB[(sb + 1) * B1];
    int shift = side ? 17 : 16;
    int mask  = side ? 0x1FFFF : 0xFFFF;
    int nd    = side ? 256 : 512;
    int dbase = side ? (b << SH_I) : (b << SH_U);
    int n     = side ? N_ITEMS : N_USERS;
    int rel   = start - side * N_EDGES;
    int* offs = side ? offs_i : offs_u;

    __shared__ int cnt[512];
    __shared__ int scn[512];
    __shared__ int wsum[4];
    if (tid < 256) { cnt[tid] = 0; cnt[256 + tid] = 0; }
    __syncthreads();

    for (int r = start + tid; r < end; r += 256)
        atomicAdd(&cnt[rec[r] >> shift], 1);
    __syncthreads();

    int a0 = cnt[2 * tid], a1 = cnt[2 * tid + 1];
    int s = a0 + a1;
    int lane = tid & 63, wid = tid >> 6;
    int x = s;
    #pragma unroll
    for (int o = 1; o < 64; o <<= 1) {
        int tt = __shfl_up(x, o);
        if (lane >= o) x += tt;
    }
    if (lane == 63) wsum[wid] = x;
    __syncthreads();
    int wbase = 0;
    for (int w = 0; w < wid; ++w) wbase += wsum[w];
    int excl = wbase + x - s;
    scn[2 * tid] = excl;
    scn[2 * tid + 1] = excl + a0;
    __syncthreads();

    for (int dl = tid; dl < nd; dl += 256) {
        int dg = dbase + dl;
        if (dg < n) offs[dg] = rel + scn[dl];
    }
    if (b == NBUK - 1 && tid == 0) offs[n] = (end - side * N_EDGES);
    __syncthreads();

    for (int r = start + tid; r < end; r += 256) {
        int v = rec[r];
        int dl = v >> shift;
        int pos = atomicAdd(&scn[dl], 1);
        list[start + pos] = (v & mask) << 7;   // byte offset of source row
    }
}

// ---- degree-balanced row schedule (counting sort by degree) ----
static __device__ __forceinline__ int row_degree(const int* offs_u, const int* offs_i, int r) {
    int d = (r < N_USERS) ? (offs_u[r + 1] - offs_u[r])
                          : (offs_i[r - N_USERS + 1] - offs_i[r - N_USERS]);
    return (d > DBINS - 1) ? DBINS - 1 : d;
}

__global__ void deg_hist_kernel(const int* __restrict__ offs_u, const int* __restrict__ offs_i,
                                int* __restrict__ dhist) {
    __shared__ int h[DBINS];
    int tid = threadIdx.x;
    if (tid < DBINS) h[tid] = 0;
    __syncthreads();
    int r = blockIdx.x * 256 + tid;
    if (r < NROWS) atomicAdd(&h[row_degree(offs_u, offs_i, r)], 1);
    __syncthreads();
    if (tid < DBINS && h[tid]) atomicAdd(&dhist[tid], h[tid]);
}

__global__ void deg_scan_kernel(const int* __restrict__ dhist, int* __restrict__ dcur) {
    int lane = threadIdx.x;   // 64 threads
    int v = dhist[lane];
    int x = v;
    #pragma unroll
    for (int o = 1; o < 64; o <<= 1) {
        int tt = __shfl_up(x, o);
        if (lane >= o) x += tt;
    }
    dcur[lane] = x - v;       // exclusive
}

__global__ void deg_build_kernel(const int* __restrict__ offs_u, const int* __restrict__ offs_i,
                                 int* __restrict__ dcur, int* __restrict__ perm) {
    __shared__ int h[DBINS];
    __shared__ int base[DBINS];
    int tid = threadIdx.x;
    if (tid < DBINS) h[tid] = 0;
    __syncthreads();
    int r = blockIdx.x * 256 + tid;
    int d = -1;
    if (r < NROWS) {
        d = row_degree(offs_u, offs_i, r);
        atomicAdd(&h[d], 1);
    }
    __syncthreads();
    if (tid < DBINS) {
        base[tid] = h[tid] ? atomicAdd(&dcur[tid], h[tid]) : 0;
        h[tid] = 0;
    }
    __syncthreads();
    if (r < NROWS) {
        int p = atomicAdd(&h[d], 1);
        perm[base[d] + p] = r;
    }
}

// ---- Fused gather: 8 rows per wave, 8 lanes per row (lane owns 8 dims).
// No cross-group fold; norm = 3 intra-group shfls. Hops 0/1 store bf16 agg
// only; final hop fuses out = init + h0 + h1 + y2.
__global__ void gather_norm_v3(const u16* __restrict__ srcU,   // table users gather from
                               const u16* __restrict__ srcI,   // table items gather from
                               const int* __restrict__ offs_u, const int* __restrict__ list_u,
                               const int* __restrict__ offs_i, const int* __restrict__ list_i,
                               const int* __restrict__ perm,
                               u16* __restrict__ aggU, u16* __restrict__ aggI,
                               const u16* __restrict__ h0U, const u16* __restrict__ h0I,
                               const u16* __restrict__ h1U, const u16* __restrict__ h1I,
                               float* __restrict__ outU, float* __restrict__ outI,
                               const float* __restrict__ initU, const float* __restrict__ initI,
                               int final_hop) {
    int t = blockIdx.x * blockDim.x + threadIdx.x;
    int lane = t & 63;
    int grp = lane >> 3, sub = lane & 7;
    int slot = (t >> 6) * 8 + grp;

    int rid = (slot < NROWS) ? perm[slot] : -1;
    bool valid = rid >= 0;
    bool isU = valid && (rid < N_USERS);
    int rr = isU ? rid : rid - N_USERS;

    int beg = 0, deg = 0;
    if (valid) {
        const int* offs = isU ? offs_u : offs_i;
        beg = offs[rr];
        deg = offs[rr + 1] - beg;
    }
    const int* list = isU ? list_u : list_i;
    const u16* src  = isU ? srcU : srcI;
    const char* srcB = (const char*)src;
    unsigned suboff = (unsigned)(sub << 4);
    const int* lp = list + beg;

    // wave-max degree (deg uniform within each 8-lane group)
    int dmax = deg;
    dmax = max(dmax, __shfl_xor(dmax, 8));
    dmax = max(dmax, __shfl_xor(dmax, 16));
    dmax = max(dmax, __shfl_xor(dmax, 32));

    float acc[8] = {0.f, 0.f, 0.f, 0.f, 0.f, 0.f, 0.f, 0.f};

    #pragma unroll 4
    for (int e = 0; e < dmax; ++e) {
        if (e < deg) {
            unsigned jb = (unsigned)lp[e];          // pre-scaled byte offset
            us8 v = *(const us8*)(srcB + (jb + suboff));
            #pragma unroll
            for (int i = 0; i < 8; ++i) acc[i] += bf2f(v[i]);
        }
    }

    // ||row||^2 over the 8-lane group
    float q = 0.f;
    #pragma unroll
    for (int i = 0; i < 8; ++i) q += acc[i] * acc[i];
    q += __shfl_xor(q, 1);
    q += __shfl_xor(q, 2);
    q += __shfl_xor(q, 4);
    float inv = 1.f / fmaxf(sqrtf(q), 1e-12f);

    if (!valid) return;
    size_t ro = (size_t)rr * EMB + (sub << 3);

    if (!final_hop) {
        u16* agg = isU ? aggU : aggI;
        us8 w;
        #pragma unroll
        for (int i = 0; i < 8; ++i) w[i] = f2bf(acc[i] * inv);
        *(us8*)(agg + ro) = w;
    } else {
        const u16* h0 = isU ? h0U : h0I;
        const u16* h1 = isU ? h1U : h1I;
        const float* init = isU ? initU : initI;
        float* out = isU ? outU : outI;
        us8 a = *(const us8*)(h0 + ro);
        us8 b = *(const us8*)(h1 + ro);
        f4 i0 = *(const f4*)(init + ro);
        f4 i1 = *(const f4*)(init + ro + 4);
        f4 r0, r1;
        r0.x = i0.x + bf2f(a[0]) + bf2f(b[0]) + acc[0] * inv;
        r0.y = i0.y + bf2f(a[1]) + bf2f(b[1]) + acc[1] * inv;
        r0.z = i0.z + bf2f(a[2]) + bf2f(b[2]) + acc[2] * inv;
        r0.w = i0.w + bf2f(a[3]) + bf2f(b[3]) + acc[3] * inv;
        r1.x = i1.x + bf2f(a[4]) + bf2f(b[4]) + acc[4] * inv;
        r1.y = i1.y + bf2f(a[5]) + bf2f(b[5]) + acc[5] * inv;
        r1.z = i1.z + bf2f(a[6]) + bf2f(b[6]) + acc[6] * inv;
        r1.w = i1.w + bf2f(a[7]) + bf2f(b[7]) + acc[7] * inv;
        *(f4*)(out + ro)     = r0;
        *(f4*)(out + ro + 4) = r1;
    }
}

extern "C" void kernel_launch(void* const* d_in, const int* in_sizes, int n_in,
                              void* d_out, int out_size, void* d_ws, size_t ws_size,
                              hipStream_t stream) {
    const float* user_emb = (const float*)d_in[0];
    const float* item_emb = (const float*)d_in[1];
    const int*   uidx     = (const int*)d_in[2];
    const int*   iidx     = (const int*)d_in[3];

    float* out      = (float*)d_out;
    float* out_item = out;                           // [N_ITEMS, 64]
    float* out_user = out + (size_t)N_ITEMS * EMB;   // [N_USERS, 64]

    // workspace layout
    u16* ws16    = (u16*)d_ws;
    u16* ua_bf   = ws16;                                   // user agg hop0
    u16* ub_bf   = ua_bf + (size_t)N_USERS * EMB;          // user agg hop1
    u16* ia_bf   = ub_bf + (size_t)N_USERS * EMB;          // item agg hop0
    u16* ib_bf   = ia_bf + (size_t)N_ITEMS * EMB;          // item agg hop1
    u16* uemb_bf = ib_bf + (size_t)N_ITEMS * EMB;
    u16* iemb_bf = uemb_bf + (size_t)N_USERS * EMB;
    int* rec     = (int*)(iemb_bf + (size_t)N_ITEMS * EMB);
    int* list    = rec + 2 * N_EDGES;
    int* list_u  = list;
    int* list_i  = list + N_EDGES;
    int* offs_u  = list + 2 * N_EDGES;
    int* offs_i  = offs_u + (N_USERS + 1);
    int* H       = offs_i + (N_ITEMS + 1);
    int* HB      = H + HN;
    int* part    = HB + HN;
    int* dhist   = part + HTILES;
    int* dcur    = dhist + DBINS;
    int* perm    = dcur + DBINS;

    // bf16 copies of the embeddings (hop-0 gather sources)
    conv_kernel<<<(N_USERS * EMB / 4 + 255) / 256, 256, 0, stream>>>(user_emb, uemb_bf, N_USERS * EMB / 4);
    conv_kernel<<<(N_ITEMS * EMB / 4 + 255) / 256, 256, 0, stream>>>(item_emb, iemb_bf, N_ITEMS * EMB / 4);

    // bucketed CSR build
    histA_kernel<<<B1, 256, 0, stream>>>(uidx, iidx, H);
    hscan_tile_kernel<<<HTILES, 256, 0, stream>>>(H, part);
    hscan_write_kernel<<<HTILES, 256, 0, stream>>>(H, part, HB);
    scatterA_kernel<<<B1, 256, 0, stream>>>(uidx, iidx, HB, rec);
    bucketB_kernel<<<2 * NBUK, 256, 0, stream>>>(HB, rec, offs_u, offs_i, list);

    // degree-balanced schedule
    hipMemsetAsync(dhist, 0, DBINS * sizeof(int), stream);
    int dblocks = (NROWS + 255) / 256;
    deg_hist_kernel<<<dblocks, 256, 0, stream>>>(offs_u, offs_i, dhist);
    deg_scan_kernel<<<1, 64, 0, stream>>>(dhist, dcur);
    deg_build_kernel<<<dblocks, 256, 0, stream>>>(offs_u, offs_i, dcur, perm);

    // 3 hops: hop0 emb->agg0, hop1 agg0->agg1, hop2 agg1->out (fused final)
    const int gthreads = ((NROWS + 7) / 8) * 64;        // one 8-lane group per row
    const int gblocks = (gthreads + 255) / 256;

    gather_norm_v3<<<gblocks, 256, 0, stream>>>(
        iemb_bf, uemb_bf, offs_u, list_u, offs_i, list_i, perm,
        ua_bf, ia_bf, nullptr, nullptr, nullptr, nullptr,
        nullptr, nullptr, nullptr, nullptr, 0);

    gather_norm_v3<<<gblocks, 256, 0, stream>>>(
        ia_bf, ua_bf, offs_u, list_u, offs_i, list_i, perm,
        ub_bf, ib_bf, nullptr, nullptr, nullptr, nullptr,
        nullptr, nullptr, nullptr, nullptr, 0);

    gather_norm_v3<<<gblocks, 256, 0, stream>>>(
        ib_bf, ub_bf, offs_u, list_u, offs_i, list_i, perm,
        nullptr, nullptr, ua_bf, ia_bf, ub_bf, ib_bf,
        out_user, out_item, user_emb, item_emb, 1);
}

// Round 8
// 239.179 us; speedup vs baseline: 1.1261x; 1.0809x over previous
//
#include <hip/hip_runtime.h>

#define N_USERS 100000
#define N_ITEMS 50000
#define NROWS (N_USERS + N_ITEMS)
#define EMB 64
#define N_EDGES 1000000

// ---- bucketed CSR build parameters ----
#define SH_U 9                 // 512 users per bucket
#define SH_I 8                 // 256 items per bucket
#define NBUK 196
#define B1 256
#define CHUNK ((N_EDGES + B1 - 1) / B1)   // 3907
#define HN (2 * NBUK * B1)
#define HTILE 4096
#define HTILES ((HN + HTILE - 1) / HTILE) // 25
#define DBINS 64

typedef unsigned short u16;
typedef u16 us8 __attribute__((ext_vector_type(8)));
typedef u16 us4 __attribute__((ext_vector_type(4)));
typedef float f4 __attribute__((ext_vector_type(4)));

static __device__ __forceinline__ float bf2f(u16 h) {
    return __uint_as_float(((unsigned)h) << 16);
}
static __device__ __forceinline__ u16 f2bf(float f) {
    unsigned u = __float_as_uint(f);
    return (u16)((u + 0x7FFFu + ((u >> 16) & 1u)) >> 16);
}

static __device__ __forceinline__ int hphys(int L) {
    int sb = L >> 8;
    int blk = L & 255;
    return blk * (2 * NBUK) + sb;
}

__global__ void conv_kernel(const float* __restrict__ a, u16* __restrict__ b, int n4) {
    int t = blockIdx.x * blockDim.x + threadIdx.x;
    if (t >= n4) return;
    f4 v = ((const f4*)a)[t];
    us4 w;
    w.x = f2bf(v.x); w.y = f2bf(v.y); w.z = f2bf(v.z); w.w = f2bf(v.w);
    ((us4*)b)[t] = w;
}

// ---- Pass A1: per-block bucket histograms ----
__global__ void histA_kernel(const int* __restrict__ uidx, const int* __restrict__ iidx,
                             int* __restrict__ H) {
    __shared__ int hu[NBUK];
    __shared__ int hi[NBUK];
    int tid = threadIdx.x, blk = blockIdx.x;
    for (int b = tid; b < NBUK; b += 256) { hu[b] = 0; hi[b] = 0; }
    __syncthreads();
    int e0 = blk * CHUNK;
    int e1 = e0 + CHUNK; if (e1 > N_EDGES) e1 = N_EDGES;
    for (int e = e0 + tid; e < e1; e += 256) {
        atomicAdd(&hu[uidx[e] >> SH_U], 1);
        atomicAdd(&hi[iidx[e] >> SH_I], 1);
    }
    __syncthreads();
    int* Hb = H + blk * (2 * NBUK);
    for (int b = tid; b < NBUK; b += 256) {
        Hb[b] = hu[b];
        Hb[NBUK + b] = hi[b];
    }
}

// ---- Pass A2: 2-level exclusive scan over logical order ----
__global__ void hscan_tile_kernel(const int* __restrict__ H, int* __restrict__ part) {
    int t = blockIdx.x, tid = threadIdx.x;
    int base = t * HTILE;
    int s = 0;
    for (int i = tid; i < HTILE; i += 256) {
        int L = base + i;
        if (L < HN) s += H[hphys(L)];
    }
    #pragma unroll
    for (int o = 32; o > 0; o >>= 1) s += __shfl_xor(s, o);
    __shared__ int wsum[4];
    if ((tid & 63) == 0) wsum[tid >> 6] = s;
    __syncthreads();
    if (tid == 0) part[t] = wsum[0] + wsum[1] + wsum[2] + wsum[3];
}

__global__ void hscan_write_kernel(const int* __restrict__ H, const int* __restrict__ part,
                                   int* __restrict__ HB) {
    int t = blockIdx.x, tid = threadIdx.x;
    int base = t * HTILE;

    __shared__ int lds[HTILE];
    for (int i = tid; i < HTILE; i += 256) {
        int L = base + i;
        lds[i] = (L < HN) ? H[hphys(L)] : 0;
    }
    __syncthreads();

    int pbase = 0;
    for (int p = 0; p < t; ++p) pbase += part[p];

    int tsum = 0;
    #pragma unroll
    for (int i = 0; i < 16; ++i) tsum += lds[tid * 16 + i];

    int lane = tid & 63, wid = tid >> 6;
    int x = tsum;
    #pragma unroll
    for (int o = 1; o < 64; o <<= 1) {
        int tt = __shfl_up(x, o);
        if (lane >= o) x += tt;
    }
    __shared__ int wsum[4];
    if (lane == 63) wsum[wid] = x;
    __syncthreads();
    int wbase = 0;
    for (int w = 0; w < wid; ++w) wbase += wsum[w];

    int run = pbase + wbase + x - tsum;
    #pragma unroll
    for (int i = 0; i < 16; ++i) {
        int L = base + tid * 16 + i;
        if (L < HN) HB[L] = run;
        run += lds[tid * 16 + i];
    }
}

// ---- Pass A3: scatter edges into bucket-segmented record array ----
__global__ void scatterA_kernel(const int* __restrict__ uidx, const int* __restrict__ iidx,
                                const int* __restrict__ HB, int* __restrict__ rec) {
    __shared__ int cu[NBUK];
    __shared__ int ci[NBUK];
    int tid = threadIdx.x, blk = blockIdx.x;
    for (int sb = tid; sb < 2 * NBUK; sb += 256) {
        int v = HB[sb * B1 + blk];
        if (sb < NBUK) cu[sb] = v; else ci[sb - NBUK] = v;
    }
    __syncthreads();
    int e0 = blk * CHUNK;
    int e1 = e0 + CHUNK; if (e1 > N_EDGES) e1 = N_EDGES;
    for (int e = e0 + tid; e < e1; e += 256) {
        int u = uidx[e];
        int i = iidx[e];
        int pu = atomicAdd(&cu[u >> SH_U], 1);
        rec[pu] = ((u & 511) << 16) | i;
        int pi = atomicAdd(&ci[i >> SH_I], 1);
        rec[pi] = ((i & 255) << 17) | u;
    }
}

// ---- Pass B: per-bucket CSR finalize (offs + byte-offset list) + in-bucket
// degree-sorted schedule (perm). A wave's 8 rows end up same-bucket AND
// degree-matched: load balance without losing line/L2 locality.
__global__ void bucketB_kernel(const int* __restrict__ HB, const int* __restrict__ rec,
                               int* __restrict__ offs_u, int* __restrict__ offs_i,
                               int* __restrict__ list, int* __restrict__ perm) {
    int sb = blockIdx.x, tid = threadIdx.x;
    int side = (sb >= NBUK) ? 1 : 0;
    int b = sb - side * NBUK;
    int start = HB[sb * B1];
    int end = (sb == 2 * NBUK - 1) ? 2 * N_EDGES : HB[(sb + 1) * B1];
    int shift = side ? 17 : 16;
    int mask  = side ? 0x1FFFF : 0xFFFF;
    int nd    = side ? 256 : 512;
    int dbase = side ? (b << SH_I) : (b << SH_U);
    int n     = side ? N_ITEMS : N_USERS;
    int rel   = start - side * N_EDGES;
    int* offs = side ? offs_i : offs_u;

    __shared__ int cnt[512];
    __shared__ int scn[512];
    __shared__ int wsum[4];
    __shared__ int dh[DBINS];
    __shared__ int dsc[DBINS];
    if (tid < 256) { cnt[tid] = 0; cnt[256 + tid] = 0; }
    if (tid < DBINS) dh[tid] = 0;
    __syncthreads();

    for (int r = start + tid; r < end; r += 256)
        atomicAdd(&cnt[rec[r] >> shift], 1);
    __syncthreads();

    int a0 = cnt[2 * tid], a1 = cnt[2 * tid + 1];
    int s = a0 + a1;
    int lane = tid & 63, wid = tid >> 6;
    int x = s;
    #pragma unroll
    for (int o = 1; o < 64; o <<= 1) {
        int tt = __shfl_up(x, o);
        if (lane >= o) x += tt;
    }
    if (lane == 63) wsum[wid] = x;
    __syncthreads();
    int wbase = 0;
    for (int w = 0; w < wid; ++w) wbase += wsum[w];
    int excl = wbase + x - s;
    scn[2 * tid] = excl;
    scn[2 * tid + 1] = excl + a0;
    __syncthreads();

    for (int dl = tid; dl < nd; dl += 256) {
        int dg = dbase + dl;
        if (dg < n) offs[dg] = rel + scn[dl];
    }
    if (b == NBUK - 1 && tid == 0) offs[n] = (end - side * N_EDGES);
    __syncthreads();

    for (int r = start + tid; r < end; r += 256) {
        int v = rec[r];
        int dl = v >> shift;
        int pos = atomicAdd(&scn[dl], 1);
        list[start + pos] = (v & mask) << 7;   // byte offset of source row
    }

    // ---- in-bucket degree sort -> perm ----
    int nv = n - dbase; if (nv > nd) nv = nd;   // valid rows in this bucket
    // histogram of degrees (cnt[] still holds per-dest degree)
    for (int dl = tid; dl < nv; dl += 256) {
        int d = cnt[dl]; if (d > DBINS - 1) d = DBINS - 1;
        atomicAdd(&dh[d], 1);
    }
    __syncthreads();
    if (tid < DBINS) {                          // wave-0 exclusive scan
        int v = dh[tid];
        int xx = v;
        #pragma unroll
        for (int o = 1; o < DBINS; o <<= 1) {
            int tt = __shfl_up(xx, o);
            if (tid >= o) xx += tt;
        }
        dsc[tid] = xx - v;
    }
    __syncthreads();
    if (tid < DBINS) dh[tid] = dsc[tid];        // cursors
    __syncthreads();
    int pwbase = side ? (N_USERS + dbase) : dbase;   // perm window base
    for (int dl = tid; dl < nv; dl += 256) {
        int d = cnt[dl]; if (d > DBINS - 1) d = DBINS - 1;
        int p = atomicAdd(&dh[d], 1);
        perm[pwbase + p] = pwbase + dl;         // global combined row id
    }
}

// ---- Fused gather: 8 rows per wave, 8 lanes per row (lane owns 8 dims).
// Hops 0/1 store bf16 agg only; final hop fuses out = init + h0 + h1 + y2.
__global__ void gather_norm_v3(const u16* __restrict__ srcU,
                               const u16* __restrict__ srcI,
                               const int* __restrict__ offs_u, const int* __restrict__ list_u,
                               const int* __restrict__ offs_i, const int* __restrict__ list_i,
                               const int* __restrict__ perm,
                               u16* __restrict__ aggU, u16* __restrict__ aggI,
                               const u16* __restrict__ h0U, const u16* __restrict__ h0I,
                               const u16* __restrict__ h1U, const u16* __restrict__ h1I,
                               float* __restrict__ outU, float* __restrict__ outI,
                               const float* __restrict__ initU, const float* __restrict__ initI,
                               int final_hop) {
    int t = blockIdx.x * blockDim.x + threadIdx.x;
    int lane = t & 63;
    int grp = lane >> 3, sub = lane & 7;
    int slot = (t >> 6) * 8 + grp;

    int rid = (slot < NROWS) ? perm[slot] : -1;
    bool valid = rid >= 0;
    bool isU = valid && (rid < N_USERS);
    int rr = isU ? rid : rid - N_USERS;

    int beg = 0, deg = 0;
    if (valid) {
        const int* offs = isU ? offs_u : offs_i;
        beg = offs[rr];
        deg = offs[rr + 1] - beg;
    }
    const int* list = isU ? list_u : list_i;
    const u16* src  = isU ? srcU : srcI;
    const char* srcB = (const char*)src;
    unsigned suboff = (unsigned)(sub << 4);
    const int* lp = list + beg;

    // wave-max degree (deg uniform within each 8-lane group)
    int dmax = deg;
    dmax = max(dmax, __shfl_xor(dmax, 8));
    dmax = max(dmax, __shfl_xor(dmax, 16));
    dmax = max(dmax, __shfl_xor(dmax, 32));

    float acc[8] = {0.f, 0.f, 0.f, 0.f, 0.f, 0.f, 0.f, 0.f};

    #pragma unroll 8
    for (int e = 0; e < dmax; ++e) {
        if (e < deg) {
            unsigned jb = (unsigned)lp[e];          // pre-scaled byte offset
            us8 v = *(const us8*)(srcB + (jb + suboff));
            #pragma unroll
            for (int i = 0; i < 8; ++i) acc[i] += bf2f(v[i]);
        }
    }

    // ||row||^2 over the 8-lane group
    float q = 0.f;
    #pragma unroll
    for (int i = 0; i < 8; ++i) q += acc[i] * acc[i];
    q += __shfl_xor(q, 1);
    q += __shfl_xor(q, 2);
    q += __shfl_xor(q, 4);
    float inv = 1.f / fmaxf(sqrtf(q), 1e-12f);

    if (!valid) return;
    size_t ro = (size_t)rr * EMB + (sub << 3);

    if (!final_hop) {
        u16* agg = isU ? aggU : aggI;
        us8 w;
        #pragma unroll
        for (int i = 0; i < 8; ++i) w[i] = f2bf(acc[i] * inv);
        *(us8*)(agg + ro) = w;
    } else {
        const u16* h0 = isU ? h0U : h0I;
        const u16* h1 = isU ? h1U : h1I;
        const float* init = isU ? initU : initI;
        float* out = isU ? outU : outI;
        us8 a = *(const us8*)(h0 + ro);
        us8 b = *(const us8*)(h1 + ro);
        f4 i0 = *(const f4*)(init + ro);
        f4 i1 = *(const f4*)(init + ro + 4);
        f4 r0, r1;
        r0.x = i0.x + bf2f(a[0]) + bf2f(b[0]) + acc[0] * inv;
        r0.y = i0.y + bf2f(a[1]) + bf2f(b[1]) + acc[1] * inv;
        r0.z = i0.z + bf2f(a[2]) + bf2f(b[2]) + acc[2] * inv;
        r0.w = i0.w + bf2f(a[3]) + bf2f(b[3]) + acc[3] * inv;
        r1.x = i1.x + bf2f(a[4]) + bf2f(b[4]) + acc[4] * inv;
        r1.y = i1.y + bf2f(a[5]) + bf2f(b[5]) + acc[5] * inv;
        r1.z = i1.z + bf2f(a[6]) + bf2f(b[6]) + acc[6] * inv;
        r1.w = i1.w + bf2f(a[7]) + bf2f(b[7]) + acc[7] * inv;
        *(f4*)(out + ro)     = r0;
        *(f4*)(out + ro + 4) = r1;
    }
}

extern "C" void kernel_launch(void* const* d_in, const int* in_sizes, int n_in,
                              void* d_out, int out_size, void* d_ws, size_t ws_size,
                              hipStream_t stream) {
    const float* user_emb = (const float*)d_in[0];
    const float* item_emb = (const float*)d_in[1];
    const int*   uidx     = (const int*)d_in[2];
    const int*   iidx     = (const int*)d_in[3];

    float* out      = (float*)d_out;
    float* out_item = out;                           // [N_ITEMS, 64]
    float* out_user = out + (size_t)N_ITEMS * EMB;   // [N_USERS, 64]

    // workspace layout
    u16* ws16    = (u16*)d_ws;
    u16* ua_bf   = ws16;                                   // user agg hop0
    u16* ub_bf   = ua_bf + (size_t)N_USERS * EMB;          // user agg hop1
    u16* ia_bf   = ub_bf + (size_t)N_USERS * EMB;          // item agg hop0
    u16* ib_bf   = ia_bf + (size_t)N_ITEMS * EMB;          // item agg hop1
    u16* uemb_bf = ib_bf + (size_t)N_ITEMS * EMB;
    u16* iemb_bf = uemb_bf + (size_t)N_USERS * EMB;
    int* rec     = (int*)(iemb_bf + (size_t)N_ITEMS * EMB);
    int* list    = rec + 2 * N_EDGES;
    int* list_u  = list;
    int* list_i  = list + N_EDGES;
    int* offs_u  = list + 2 * N_EDGES;
    int* offs_i  = offs_u + (N_USERS + 1);
    int* H       = offs_i + (N_ITEMS + 1);
    int* HB      = H + HN;
    int* part    = HB + HN;
    int* perm    = part + HTILES;

    // bf16 copies of the embeddings (hop-0 gather sources)
    conv_kernel<<<(N_USERS * EMB / 4 + 255) / 256, 256, 0, stream>>>(user_emb, uemb_bf, N_USERS * EMB / 4);
    conv_kernel<<<(N_ITEMS * EMB / 4 + 255) / 256, 256, 0, stream>>>(item_emb, iemb_bf, N_ITEMS * EMB / 4);

    // bucketed CSR build (+ in-bucket degree-sorted schedule)
    histA_kernel<<<B1, 256, 0, stream>>>(uidx, iidx, H);
    hscan_tile_kernel<<<HTILES, 256, 0, stream>>>(H, part);
    hscan_write_kernel<<<HTILES, 256, 0, stream>>>(H, part, HB);
    scatterA_kernel<<<B1, 256, 0, stream>>>(uidx, iidx, HB, rec);
    bucketB_kernel<<<2 * NBUK, 256, 0, stream>>>(HB, rec, offs_u, offs_i, list, perm);

    // 3 hops: hop0 emb->agg0, hop1 agg0->agg1, hop2 agg1->out (fused final)
    const int gthreads = ((NROWS + 7) / 8) * 64;        // one 8-lane group per row
    const int gblocks = (gthreads + 255) / 256;

    gather_norm_v3<<<gblocks, 256, 0, stream>>>(
        iemb_bf, uemb_bf, offs_u, list_u, offs_i, list_i, perm,
        ua_bf, ia_bf, nullptr, nullptr, nullptr, nullptr,
        nullptr, nullptr, nullptr, nullptr, 0);

    gather_norm_v3<<<gblocks, 256, 0, stream>>>(
        ia_bf, ua_bf, offs_u, list_u, offs_i, list_i, perm,
        ub_bf, ib_bf, nullptr, nullptr, nullptr, nullptr,
        nullptr, nullptr, nullptr, nullptr, 0);

    gather_norm_v3<<<gblocks, 256, 0, stream>>>(
        ib_bf, ub_bf, offs_u, list_u, offs_i, list_i, perm,
        nullptr, nullptr, ua_bf, ia_bf, ub_bf, ib_bf,
        out_user, out_item, user_emb, item_emb, 1);
}

// Round 9
// 228.542 us; speedup vs baseline: 1.1785x; 1.0465x over previous
//
#include <hip/hip_runtime.h>

#define N_USERS 100000
#define N_ITEMS 50000
#define NROWS (N_USERS + N_ITEMS)
#define EMB 64
#define N_EDGES 1000000

// ---- bucketed CSR build parameters ----
#define SH_U 9                 // 512 users per bucket
#define SH_I 8                 // 256 items per bucket
#define NBUK 196
#define B1 256
#define CHUNK ((N_EDGES + B1 - 1) / B1)   // 3907
#define HN (2 * NBUK * B1)
#define HTILE 4096
#define HTILES ((HN + HTILE - 1) / HTILE) // 25
#define DBINS 64

typedef unsigned short u16;
typedef u16 us8 __attribute__((ext_vector_type(8)));
typedef u16 us4 __attribute__((ext_vector_type(4)));
typedef float f4 __attribute__((ext_vector_type(4)));

static __device__ __forceinline__ float bf2f(u16 h) {
    return __uint_as_float(((unsigned)h) << 16);
}
static __device__ __forceinline__ u16 f2bf(float f) {
    unsigned u = __float_as_uint(f);
    return (u16)((u + 0x7FFFu + ((u >> 16) & 1u)) >> 16);
}

static __device__ __forceinline__ int hphys(int L) {
    int sb = L >> 8;
    int blk = L & 255;
    return blk * (2 * NBUK) + sb;
}

// f32 -> bf16, both tables in one launch
__global__ void conv_kernel(const float* __restrict__ ua, u16* __restrict__ ub,
                            const float* __restrict__ ia, u16* __restrict__ ib) {
    const int un4 = N_USERS * EMB / 4;
    const int in4 = N_ITEMS * EMB / 4;
    int t = blockIdx.x * blockDim.x + threadIdx.x;
    const float* a; u16* b; int idx;
    if (t < un4) { a = ua; b = ub; idx = t; }
    else if (t < un4 + in4) { a = ia; b = ib; idx = t - un4; }
    else return;
    f4 v = ((const f4*)a)[idx];
    us4 w;
    w.x = f2bf(v.x); w.y = f2bf(v.y); w.z = f2bf(v.z); w.w = f2bf(v.w);
    ((us4*)b)[idx] = w;
}

// ---- Pass A1: per-block bucket histograms ----
__global__ void histA_kernel(const int* __restrict__ uidx, const int* __restrict__ iidx,
                             int* __restrict__ H) {
    __shared__ int hu[NBUK];
    __shared__ int hi[NBUK];
    int tid = threadIdx.x, blk = blockIdx.x;
    for (int b = tid; b < NBUK; b += 256) { hu[b] = 0; hi[b] = 0; }
    __syncthreads();
    int e0 = blk * CHUNK;
    int e1 = e0 + CHUNK; if (e1 > N_EDGES) e1 = N_EDGES;
    for (int e = e0 + tid; e < e1; e += 256) {
        atomicAdd(&hu[uidx[e] >> SH_U], 1);
        atomicAdd(&hi[iidx[e] >> SH_I], 1);
    }
    __syncthreads();
    int* Hb = H + blk * (2 * NBUK);
    for (int b = tid; b < NBUK; b += 256) {
        Hb[b] = hu[b];
        Hb[NBUK + b] = hi[b];
    }
}

// ---- Pass A2: 2-level exclusive scan over logical order ----
__global__ void hscan_tile_kernel(const int* __restrict__ H, int* __restrict__ part) {
    int t = blockIdx.x, tid = threadIdx.x;
    int base = t * HTILE;
    int s = 0;
    for (int i = tid; i < HTILE; i += 256) {
        int L = base + i;
        if (L < HN) s += H[hphys(L)];
    }
    #pragma unroll
    for (int o = 32; o > 0; o >>= 1) s += __shfl_xor(s, o);
    __shared__ int wsum[4];
    if ((tid & 63) == 0) wsum[tid >> 6] = s;
    __syncthreads();
    if (tid == 0) part[t] = wsum[0] + wsum[1] + wsum[2] + wsum[3];
}

__global__ void hscan_write_kernel(const int* __restrict__ H, const int* __restrict__ part,
                                   int* __restrict__ HB) {
    int t = blockIdx.x, tid = threadIdx.x;
    int base = t * HTILE;

    __shared__ int lds[HTILE];
    for (int i = tid; i < HTILE; i += 256) {
        int L = base + i;
        lds[i] = (L < HN) ? H[hphys(L)] : 0;
    }
    __syncthreads();

    int pbase = 0;
    for (int p = 0; p < t; ++p) pbase += part[p];

    int tsum = 0;
    #pragma unroll
    for (int i = 0; i < 16; ++i) tsum += lds[tid * 16 + i];

    int lane = tid & 63, wid = tid >> 6;
    int x = tsum;
    #pragma unroll
    for (int o = 1; o < 64; o <<= 1) {
        int tt = __shfl_up(x, o);
        if (lane >= o) x += tt;
    }
    __shared__ int wsum[4];
    if (lane == 63) wsum[wid] = x;
    __syncthreads();
    int wbase = 0;
    for (int w = 0; w < wid; ++w) wbase += wsum[w];

    int run = pbase + wbase + x - tsum;
    #pragma unroll
    for (int i = 0; i < 16; ++i) {
        int L = base + tid * 16 + i;
        if (L < HN) HB[L] = run;
        run += lds[tid * 16 + i];
    }
}

// ---- Pass A3: scatter edges into bucket-segmented record array ----
__global__ void scatterA_kernel(const int* __restrict__ uidx, const int* __restrict__ iidx,
                                const int* __restrict__ HB, int* __restrict__ rec) {
    __shared__ int cu[NBUK];
    __shared__ int ci[NBUK];
    int tid = threadIdx.x, blk = blockIdx.x;
    for (int sb = tid; sb < 2 * NBUK; sb += 256) {
        int v = HB[sb * B1 + blk];
        if (sb < NBUK) cu[sb] = v; else ci[sb - NBUK] = v;
    }
    __syncthreads();
    int e0 = blk * CHUNK;
    int e1 = e0 + CHUNK; if (e1 > N_EDGES) e1 = N_EDGES;
    for (int e = e0 + tid; e < e1; e += 256) {
        int u = uidx[e];
        int i = iidx[e];
        int pu = atomicAdd(&cu[u >> SH_U], 1);
        rec[pu] = ((u & 511) << 16) | i;
        int pi = atomicAdd(&ci[i >> SH_I], 1);
        rec[pi] = ((i & 255) << 17) | u;
    }
}

// ---- Pass B: per-bucket CSR finalize (byte-offset list) + degree-sorted
// packed slot descriptors: desc[slot] = {absBeg, (rid<<9)|deg}.
__global__ void bucketB_kernel(const int* __restrict__ HB, const int* __restrict__ rec,
                               int* __restrict__ list, int2* __restrict__ desc) {
    int sb = blockIdx.x, tid = threadIdx.x;
    int side = (sb >= NBUK) ? 1 : 0;
    int b = sb - side * NBUK;
    int start = HB[sb * B1];
    int end = (sb == 2 * NBUK - 1) ? 2 * N_EDGES : HB[(sb + 1) * B1];
    int shift = side ? 17 : 16;
    int mask  = side ? 0x1FFFF : 0xFFFF;
    int nd    = side ? 256 : 512;
    int dbase = side ? (b << SH_I) : (b << SH_U);
    int n     = side ? N_ITEMS : N_USERS;

    __shared__ int cnt[512];
    __shared__ int scn[512];
    __shared__ int wsum[4];
    __shared__ int dh[DBINS];
    __shared__ int dsc[DBINS];
    if (tid < 256) { cnt[tid] = 0; cnt[256 + tid] = 0; }
    if (tid < DBINS) dh[tid] = 0;
    __syncthreads();

    for (int r = start + tid; r < end; r += 256)
        atomicAdd(&cnt[rec[r] >> shift], 1);
    __syncthreads();

    int a0 = cnt[2 * tid], a1 = cnt[2 * tid + 1];
    int s = a0 + a1;
    int lane = tid & 63, wid = tid >> 6;
    int x = s;
    #pragma unroll
    for (int o = 1; o < 64; o <<= 1) {
        int tt = __shfl_up(x, o);
        if (lane >= o) x += tt;
    }
    if (lane == 63) wsum[wid] = x;
    __syncthreads();
    int wbase = 0;
    for (int w = 0; w < wid; ++w) wbase += wsum[w];
    int excl = wbase + x - s;
    scn[2 * tid] = excl;
    scn[2 * tid + 1] = excl + a0;
    __syncthreads();

    for (int r = start + tid; r < end; r += 256) {
        int v = rec[r];
        int dl = v >> shift;
        int pos = atomicAdd(&scn[dl], 1);
        list[start + pos] = (v & mask) << 7;   // byte offset of source row
    }
    __syncthreads();                            // scn now holds END offsets

    // ---- in-bucket degree sort -> packed descriptors ----
    int nv = n - dbase; if (nv > nd) nv = nd;
    for (int dl = tid; dl < nv; dl += 256) {
        int d = cnt[dl]; if (d > DBINS - 1) d = DBINS - 1;
        atomicAdd(&dh[d], 1);
    }
    __syncthreads();
    if (tid < DBINS) {
        int v = dh[tid];
        int xx = v;
        #pragma unroll
        for (int o = 1; o < DBINS; o <<= 1) {
            int tt = __shfl_up(xx, o);
            if (tid >= o) xx += tt;
        }
        dsc[tid] = xx - v;
    }
    __syncthreads();
    if (tid < DBINS) dh[tid] = dsc[tid];
    __syncthreads();
    int pwbase = side ? (N_USERS + dbase) : dbase;
    for (int dl = tid; dl < nv; dl += 256) {
        int deg = cnt[dl];
        int d = deg; if (d > DBINS - 1) d = DBINS - 1;
        int p = atomicAdd(&dh[d], 1);
        int absBeg = start + scn[dl] - deg;     // element index into combined list
        int rid = pwbase + dl;                  // combined row id
        desc[pwbase + p] = make_int2(absBeg, (rid << 9) | deg);
    }
}

// ---- Fused gather: 8 rows per wave, 8 lanes per row (lane owns 8 dims).
// desc gives {list beg, rid, deg} in one 8B load. One staged list load per
// 8 edges + shfl broadcast. Hops 0/1 store bf16 agg; final hop fuses
// out = init + h0 + h1 + y2.
__global__ void gather_norm_v4(const u16* __restrict__ srcU,
                               const u16* __restrict__ srcI,
                               const int* __restrict__ list,
                               const int2* __restrict__ desc,
                               u16* __restrict__ aggU, u16* __restrict__ aggI,
                               const u16* __restrict__ h0U, const u16* __restrict__ h0I,
                               const u16* __restrict__ h1U, const u16* __restrict__ h1I,
                               float* __restrict__ outU, float* __restrict__ outI,
                               const float* __restrict__ initU, const float* __restrict__ initI,
                               int final_hop) {
    // XCD-chunked bijective swizzle (grid 4688 = 8 * 586)
    int bid = blockIdx.x;
    int wg = (bid & 7) * 586 + (bid >> 3);

    int t = wg * 256 + threadIdx.x;
    int lane = t & 63;
    int grp = lane >> 3, sub = lane & 7;
    int slot = (t >> 6) * 8 + grp;

    int beg = 0, deg = 0, rid = 0;
    bool valid = slot < NROWS;
    if (valid) {
        int2 d2 = desc[slot];
        beg = d2.x;
        deg = d2.y & 511;
        rid = d2.y >> 9;
    }
    bool isU = rid < N_USERS;
    int rr = isU ? rid : rid - N_USERS;

    const u16* src  = isU ? srcU : srcI;
    const char* srcB = (const char*)src;
    unsigned suboff = (unsigned)(sub << 4);
    const int* lp = list + beg;

    // wave-max degree (deg uniform within each 8-lane group)
    int dmax = deg;
    dmax = max(dmax, __shfl_xor(dmax, 8));
    dmax = max(dmax, __shfl_xor(dmax, 16));
    dmax = max(dmax, __shfl_xor(dmax, 32));

    float acc[8] = {0.f, 0.f, 0.f, 0.f, 0.f, 0.f, 0.f, 0.f};

    int lbase = lane & 56;                     // grp*8: shfl source base
    int nbatch = (dmax + 7) >> 3;
    for (int bch = 0; bch < nbatch; ++bch) {
        int ebase = bch << 3;
        int jb_l = lp[ebase + sub];            // 1 coalesced load per 8 edges
        #pragma unroll
        for (int e = 0; e < 8; ++e) {
            if (ebase + e < deg) {
                unsigned jb = (unsigned)__shfl(jb_l, lbase | e);
                us8 v = *(const us8*)(srcB + (jb + suboff));
                #pragma unroll
                for (int i = 0; i < 8; ++i) acc[i] += bf2f(v[i]);
            }
        }
    }

    // ||row||^2 over the 8-lane group
    float q = 0.f;
    #pragma unroll
    for (int i = 0; i < 8; ++i) q += acc[i] * acc[i];
    q += __shfl_xor(q, 1);
    q += __shfl_xor(q, 2);
    q += __shfl_xor(q, 4);
    float inv = 1.f / fmaxf(sqrtf(q), 1e-12f);

    if (!valid) return;
    size_t ro = (size_t)rr * EMB + (sub << 3);

    if (!final_hop) {
        u16* agg = isU ? aggU : aggI;
        us8 w;
        #pragma unroll
        for (int i = 0; i < 8; ++i) w[i] = f2bf(acc[i] * inv);
        *(us8*)(agg + ro) = w;
    } else {
        const u16* h0 = isU ? h0U : h0I;
        const u16* h1 = isU ? h1U : h1I;
        const float* init = isU ? initU : initI;
        float* out = isU ? outU : outI;
        us8 a = *(const us8*)(h0 + ro);
        us8 b = *(const us8*)(h1 + ro);
        f4 i0 = *(const f4*)(init + ro);
        f4 i1 = *(const f4*)(init + ro + 4);
        f4 r0, r1;
        r0.x = i0.x + bf2f(a[0]) + bf2f(b[0]) + acc[0] * inv;
        r0.y = i0.y + bf2f(a[1]) + bf2f(b[1]) + acc[1] * inv;
        r0.z = i0.z + bf2f(a[2]) + bf2f(b[2]) + acc[2] * inv;
        r0.w = i0.w + bf2f(a[3]) + bf2f(b[3]) + acc[3] * inv;
        r1.x = i1.x + bf2f(a[4]) + bf2f(b[4]) + acc[4] * inv;
        r1.y = i1.y + bf2f(a[5]) + bf2f(b[5]) + acc[5] * inv;
        r1.z = i1.z + bf2f(a[6]) + bf2f(b[6]) + acc[6] * inv;
        r1.w = i1.w + bf2f(a[7]) + bf2f(b[7]) + acc[7] * inv;
        *(f4*)(out + ro)     = r0;
        *(f4*)(out + ro + 4) = r1;
    }
}

extern "C" void kernel_launch(void* const* d_in, const int* in_sizes, int n_in,
                              void* d_out, int out_size, void* d_ws, size_t ws_size,
                              hipStream_t stream) {
    const float* user_emb = (const float*)d_in[0];
    const float* item_emb = (const float*)d_in[1];
    const int*   uidx     = (const int*)d_in[2];
    const int*   iidx     = (const int*)d_in[3];

    float* out      = (float*)d_out;
    float* out_item = out;                           // [N_ITEMS, 64]
    float* out_user = out + (size_t)N_ITEMS * EMB;   // [N_USERS, 64]

    // workspace layout
    u16* ws16    = (u16*)d_ws;
    u16* ua_bf   = ws16;                                   // user agg hop0
    u16* ub_bf   = ua_bf + (size_t)N_USERS * EMB;          // user agg hop1
    u16* ia_bf   = ub_bf + (size_t)N_USERS * EMB;          // item agg hop0
    u16* ib_bf   = ia_bf + (size_t)N_ITEMS * EMB;          // item agg hop1
    u16* uemb_bf = ib_bf + (size_t)N_ITEMS * EMB;
    u16* iemb_bf = uemb_bf + (size_t)N_USERS * EMB;
    int* rec     = (int*)(iemb_bf + (size_t)N_ITEMS * EMB);
    int* list    = rec + 2 * N_EDGES;
    int* H       = list + 2 * N_EDGES + 16;   // +16 pad: staged list tail reads
    int* HB      = H + HN;
    int* part    = HB + HN;
    int2* desc   = (int2*)(part + HTILES + 1);  // 8B aligned region

    // bf16 copies of the embeddings (hop-0 gather sources)
    conv_kernel<<<(NROWS * EMB / 4 + 255) / 256, 256, 0, stream>>>(user_emb, uemb_bf, item_emb, iemb_bf);

    // bucketed CSR build (+ in-bucket degree-sorted packed descriptors)
    histA_kernel<<<B1, 256, 0, stream>>>(uidx, iidx, H);
    hscan_tile_kernel<<<HTILES, 256, 0, stream>>>(H, part);
    hscan_write_kernel<<<HTILES, 256, 0, stream>>>(H, part, HB);
    scatterA_kernel<<<B1, 256, 0, stream>>>(uidx, iidx, HB, rec);
    bucketB_kernel<<<2 * NBUK, 256, 0, stream>>>(HB, rec, list, desc);

    // 3 hops: hop0 emb->agg0, hop1 agg0->agg1, hop2 agg1->out (fused final)
    const int gblocks = 4688;   // ceil(ceil(NROWS/8)*64 / 256), = 8*586 exactly

    gather_norm_v4<<<gblocks, 256, 0, stream>>>(
        iemb_bf, uemb_bf, list, desc,
        ua_bf, ia_bf, nullptr, nullptr, nullptr, nullptr,
        nullptr, nullptr, nullptr, nullptr, 0);

    gather_norm_v4<<<gblocks, 256, 0, stream>>>(
        ia_bf, ua_bf, list, desc,
        ub_bf, ib_bf, nullptr, nullptr, nullptr, nullptr,
        nullptr, nullptr, nullptr, nullptr, 0);

    gather_norm_v4<<<gblocks, 256, 0, stream>>>(
        ib_bf, ub_bf, list, desc,
        nullptr, nullptr, ua_bf, ia_bf, ub_bf, ib_bf,
        out_user, out_item, user_emb, item_emb, 1);
}

// Round 10
// 208.604 us; speedup vs baseline: 1.2911x; 1.0956x over previous
//
#include <hip/hip_runtime.h>

#define N_USERS 100000
#define N_ITEMS 50000
#define NROWS (N_USERS + N_ITEMS)
#define EMB 64
#define N_EDGES 1000000

// ---- bucketed CSR build parameters ----
#define SH_U 9                 // 512 users per bucket
#define SH_I 8                 // 256 items per bucket
#define NBUK 196
#define B1 256
#define CHUNK ((N_EDGES + B1 - 1) / B1)   // 3907
#define HN (2 * NBUK * B1)
#define HTILE 4096
#define HTILES ((HN + HTILE - 1) / HTILE) // 25
#define DBINS 64

typedef unsigned short u16;
typedef u16 us8 __attribute__((ext_vector_type(8)));
typedef u16 us4 __attribute__((ext_vector_type(4)));
typedef float f4 __attribute__((ext_vector_type(4)));

static __device__ __forceinline__ float bf2f(u16 h) {
    return __uint_as_float(((unsigned)h) << 16);
}
static __device__ __forceinline__ u16 f2bf(float f) {
    unsigned u = __float_as_uint(f);
    return (u16)((u + 0x7FFFu + ((u >> 16) & 1u)) >> 16);
}

static __device__ __forceinline__ int hphys(int L) {
    int sb = L >> 8;
    int blk = L & 255;
    return blk * (2 * NBUK) + sb;
}

// f32 -> bf16, both tables in one launch
__global__ void conv_kernel(const float* __restrict__ ua, u16* __restrict__ ub,
                            const float* __restrict__ ia, u16* __restrict__ ib) {
    const int un4 = N_USERS * EMB / 4;
    const int in4 = N_ITEMS * EMB / 4;
    int t = blockIdx.x * blockDim.x + threadIdx.x;
    const float* a; u16* b; int idx;
    if (t < un4) { a = ua; b = ub; idx = t; }
    else if (t < un4 + in4) { a = ia; b = ib; idx = t - un4; }
    else return;
    f4 v = ((const f4*)a)[idx];
    us4 w;
    w.x = f2bf(v.x); w.y = f2bf(v.y); w.z = f2bf(v.z); w.w = f2bf(v.w);
    ((us4*)b)[idx] = w;
}

// ---- Pass A1: per-block bucket histograms ----
__global__ void histA_kernel(const int* __restrict__ uidx, const int* __restrict__ iidx,
                             int* __restrict__ H) {
    __shared__ int hu[NBUK];
    __shared__ int hi[NBUK];
    int tid = threadIdx.x, blk = blockIdx.x;
    for (int b = tid; b < NBUK; b += 256) { hu[b] = 0; hi[b] = 0; }
    __syncthreads();
    int e0 = blk * CHUNK;
    int e1 = e0 + CHUNK; if (e1 > N_EDGES) e1 = N_EDGES;
    for (int e = e0 + tid; e < e1; e += 256) {
        atomicAdd(&hu[uidx[e] >> SH_U], 1);
        atomicAdd(&hi[iidx[e] >> SH_I], 1);
    }
    __syncthreads();
    int* Hb = H + blk * (2 * NBUK);
    for (int b = tid; b < NBUK; b += 256) {
        Hb[b] = hu[b];
        Hb[NBUK + b] = hi[b];
    }
}

// ---- Pass A2: 2-level exclusive scan over logical order ----
__global__ void hscan_tile_kernel(const int* __restrict__ H, int* __restrict__ part) {
    int t = blockIdx.x, tid = threadIdx.x;
    int base = t * HTILE;
    int s = 0;
    for (int i = tid; i < HTILE; i += 256) {
        int L = base + i;
        if (L < HN) s += H[hphys(L)];
    }
    #pragma unroll
    for (int o = 32; o > 0; o >>= 1) s += __shfl_xor(s, o);
    __shared__ int wsum[4];
    if ((tid & 63) == 0) wsum[tid >> 6] = s;
    __syncthreads();
    if (tid == 0) part[t] = wsum[0] + wsum[1] + wsum[2] + wsum[3];
}

__global__ void hscan_write_kernel(const int* __restrict__ H, const int* __restrict__ part,
                                   int* __restrict__ HB) {
    int t = blockIdx.x, tid = threadIdx.x;
    int base = t * HTILE;

    __shared__ int lds[HTILE];
    for (int i = tid; i < HTILE; i += 256) {
        int L = base + i;
        lds[i] = (L < HN) ? H[hphys(L)] : 0;
    }
    __syncthreads();

    int pbase = 0;
    for (int p = 0; p < t; ++p) pbase += part[p];

    int tsum = 0;
    #pragma unroll
    for (int i = 0; i < 16; ++i) tsum += lds[tid * 16 + i];

    int lane = tid & 63, wid = tid >> 6;
    int x = tsum;
    #pragma unroll
    for (int o = 1; o < 64; o <<= 1) {
        int tt = __shfl_up(x, o);
        if (lane >= o) x += tt;
    }
    __shared__ int wsum[4];
    if (lane == 63) wsum[wid] = x;
    __syncthreads();
    int wbase = 0;
    for (int w = 0; w < wid; ++w) wbase += wsum[w];

    int run = pbase + wbase + x - tsum;
    #pragma unroll
    for (int i = 0; i < 16; ++i) {
        int L = base + tid * 16 + i;
        if (L < HN) HB[L] = run;
        run += lds[tid * 16 + i];
    }
}

// ---- Pass A3: scatter edges into bucket-segmented record array ----
__global__ void scatterA_kernel(const int* __restrict__ uidx, const int* __restrict__ iidx,
                                const int* __restrict__ HB, int* __restrict__ rec) {
    __shared__ int cu[NBUK];
    __shared__ int ci[NBUK];
    int tid = threadIdx.x, blk = blockIdx.x;
    for (int sb = tid; sb < 2 * NBUK; sb += 256) {
        int v = HB[sb * B1 + blk];
        if (sb < NBUK) cu[sb] = v; else ci[sb - NBUK] = v;
    }
    __syncthreads();
    int e0 = blk * CHUNK;
    int e1 = e0 + CHUNK; if (e1 > N_EDGES) e1 = N_EDGES;
    for (int e = e0 + tid; e < e1; e += 256) {
        int u = uidx[e];
        int i = iidx[e];
        int pu = atomicAdd(&cu[u >> SH_U], 1);
        rec[pu] = ((u & 511) << 16) | i;
        int pi = atomicAdd(&ci[i >> SH_I], 1);
        rec[pi] = ((i & 255) << 17) | u;
    }
}

// ---- Pass B: per-bucket CSR finalize (byte-offset list) + degree-sorted
// packed slot descriptors: desc[slot] = {absBeg, (rid<<9)|deg}.
__global__ void bucketB_kernel(const int* __restrict__ HB, const int* __restrict__ rec,
                               int* __restrict__ list, int2* __restrict__ desc) {
    int sb = blockIdx.x, tid = threadIdx.x;
    int side = (sb >= NBUK) ? 1 : 0;
    int b = sb - side * NBUK;
    int start = HB[sb * B1];
    int end = (sb == 2 * NBUK - 1) ? 2 * N_EDGES : HB[(sb + 1) * B1];
    int shift = side ? 17 : 16;
    int mask  = side ? 0x1FFFF : 0xFFFF;
    int nd    = side ? 256 : 512;
    int dbase = side ? (b << SH_I) : (b << SH_U);
    int n     = side ? N_ITEMS : N_USERS;

    __shared__ int cnt[512];
    __shared__ int scn[512];
    __shared__ int wsum[4];
    __shared__ int dh[DBINS];
    __shared__ int dsc[DBINS];
    if (tid < 256) { cnt[tid] = 0; cnt[256 + tid] = 0; }
    if (tid < DBINS) dh[tid] = 0;
    __syncthreads();

    for (int r = start + tid; r < end; r += 256)
        atomicAdd(&cnt[rec[r] >> shift], 1);
    __syncthreads();

    int a0 = cnt[2 * tid], a1 = cnt[2 * tid + 1];
    int s = a0 + a1;
    int lane = tid & 63, wid = tid >> 6;
    int x = s;
    #pragma unroll
    for (int o = 1; o < 64; o <<= 1) {
        int tt = __shfl_up(x, o);
        if (lane >= o) x += tt;
    }
    if (lane == 63) wsum[wid] = x;
    __syncthreads();
    int wbase = 0;
    for (int w = 0; w < wid; ++w) wbase += wsum[w];
    int excl = wbase + x - s;
    scn[2 * tid] = excl;
    scn[2 * tid + 1] = excl + a0;
    __syncthreads();

    for (int r = start + tid; r < end; r += 256) {
        int v = rec[r];
        int dl = v >> shift;
        int pos = atomicAdd(&scn[dl], 1);
        list[start + pos] = (v & mask) << 7;   // byte offset of source row
    }
    __syncthreads();                            // scn now holds END offsets

    // ---- in-bucket degree sort -> packed descriptors ----
    int nv = n - dbase; if (nv > nd) nv = nd;
    for (int dl = tid; dl < nv; dl += 256) {
        int d = cnt[dl]; if (d > DBINS - 1) d = DBINS - 1;
        atomicAdd(&dh[d], 1);
    }
    __syncthreads();
    if (tid < DBINS) {
        int v = dh[tid];
        int xx = v;
        #pragma unroll
        for (int o = 1; o < DBINS; o <<= 1) {
            int tt = __shfl_up(xx, o);
            if (tid >= o) xx += tt;
        }
        dsc[tid] = xx - v;
    }
    __syncthreads();
    if (tid < DBINS) dh[tid] = dsc[tid];
    __syncthreads();
    int pwbase = side ? (N_USERS + dbase) : dbase;
    for (int dl = tid; dl < nv; dl += 256) {
        int deg = cnt[dl];
        int d = deg; if (d > DBINS - 1) d = DBINS - 1;
        int p = atomicAdd(&dh[d], 1);
        int absBeg = start + scn[dl] - deg;     // element index into combined list
        int rid = pwbase + dl;                  // combined row id
        desc[pwbase + p] = make_int2(absBeg, (rid << 9) | deg);
    }
}

// ---- Fused gather: 8 rows per wave, 8 lanes per row (lane owns 8 dims).
// Degree-uniform groups -> unconditional 16-edge super-batches (deep MLP),
// one 8-batch, single predicated tail. Hops 0/1 store bf16 agg; final hop
// fuses out = init + h0 + h1 + y2.
__global__ void gather_norm_v5(const u16* __restrict__ srcU,
                               const u16* __restrict__ srcI,
                               const int* __restrict__ list,
                               const int2* __restrict__ desc,
                               u16* __restrict__ aggU, u16* __restrict__ aggI,
                               const u16* __restrict__ h0U, const u16* __restrict__ h0I,
                               const u16* __restrict__ h1U, const u16* __restrict__ h1I,
                               float* __restrict__ outU, float* __restrict__ outI,
                               const float* __restrict__ initU, const float* __restrict__ initI,
                               int final_hop) {
    // XCD-chunked bijective swizzle (grid 4688 = 8 * 586)
    int bid = blockIdx.x;
    int wg = (bid & 7) * 586 + (bid >> 3);

    int t = wg * 256 + threadIdx.x;
    int lane = t & 63;
    int grp = lane >> 3, sub = lane & 7;
    int slot = (t >> 6) * 8 + grp;

    int beg = 0, deg = 0, rid = 0;
    bool valid = slot < NROWS;
    if (valid) {
        int2 d2 = desc[slot];
        beg = d2.x;
        deg = d2.y & 511;
        rid = d2.y >> 9;
    }
    bool isU = rid < N_USERS;
    int rr = isU ? rid : rid - N_USERS;

    const u16* src  = isU ? srcU : srcI;
    const char* srcB = (const char*)src;
    unsigned suboff = (unsigned)(sub << 4);
    const int* lp = list + beg;

    float acc[8] = {0.f, 0.f, 0.f, 0.f, 0.f, 0.f, 0.f, 0.f};

    int lbase = lane & 56;                     // grp*8: shfl source base
    int nfull16 = deg >> 4;                    // group-uniform (degree-sorted)
    int e0 = 0;
    for (int b16 = 0; b16 < nfull16; ++b16) {
        int jba = lp[e0 + sub];                // 2 list loads -> 16 edges
        int jbb = lp[e0 + 8 + sub];
        #pragma unroll
        for (int e = 0; e < 8; ++e) {
            unsigned jb = (unsigned)__shfl(jba, lbase | e);
            us8 v = *(const us8*)(srcB + (jb + suboff));
            #pragma unroll
            for (int i = 0; i < 8; ++i) acc[i] += bf2f(v[i]);
        }
        #pragma unroll
        for (int e = 0; e < 8; ++e) {
            unsigned jb = (unsigned)__shfl(jbb, lbase | e);
            us8 v = *(const us8*)(srcB + (jb + suboff));
            #pragma unroll
            for (int i = 0; i < 8; ++i) acc[i] += bf2f(v[i]);
        }
        e0 += 16;
    }
    if (deg & 8) {                             // one unconditional 8-batch
        int jba = lp[e0 + sub];
        #pragma unroll
        for (int e = 0; e < 8; ++e) {
            unsigned jb = (unsigned)__shfl(jba, lbase | e);
            us8 v = *(const us8*)(srcB + (jb + suboff));
            #pragma unroll
            for (int i = 0; i < 8; ++i) acc[i] += bf2f(v[i]);
        }
        e0 += 8;
    }
    int rem = deg & 7;
    if (rem) {                                 // single predicated tail batch
        int jba = lp[e0 + sub];                // may over-read into pad (safe)
        #pragma unroll
        for (int e = 0; e < 8; ++e) {
            if (e < rem) {
                unsigned jb = (unsigned)__shfl(jba, lbase | e);
                us8 v = *(const us8*)(srcB + (jb + suboff));
                #pragma unroll
                for (int i = 0; i < 8; ++i) acc[i] += bf2f(v[i]);
            }
        }
    }

    // ||row||^2 over the 8-lane group
    float q = 0.f;
    #pragma unroll
    for (int i = 0; i < 8; ++i) q += acc[i] * acc[i];
    q += __shfl_xor(q, 1);
    q += __shfl_xor(q, 2);
    q += __shfl_xor(q, 4);
    float inv = 1.f / fmaxf(sqrtf(q), 1e-12f);

    if (!valid) return;
    size_t ro = (size_t)rr * EMB + (sub << 3);

    if (!final_hop) {
        u16* agg = isU ? aggU : aggI;
        us8 w;
        #pragma unroll
        for (int i = 0; i < 8; ++i) w[i] = f2bf(acc[i] * inv);
        *(us8*)(agg + ro) = w;
    } else {
        const u16* h0 = isU ? h0U : h0I;
        const u16* h1 = isU ? h1U : h1I;
        const float* init = isU ? initU : initI;
        float* out = isU ? outU : outI;
        us8 a = *(const us8*)(h0 + ro);
        us8 b = *(const us8*)(h1 + ro);
        f4 i0 = *(const f4*)(init + ro);
        f4 i1 = *(const f4*)(init + ro + 4);
        f4 r0, r1;
        r0.x = i0.x + bf2f(a[0]) + bf2f(b[0]) + acc[0] * inv;
        r0.y = i0.y + bf2f(a[1]) + bf2f(b[1]) + acc[1] * inv;
        r0.z = i0.z + bf2f(a[2]) + bf2f(b[2]) + acc[2] * inv;
        r0.w = i0.w + bf2f(a[3]) + bf2f(b[3]) + acc[3] * inv;
        r1.x = i1.x + bf2f(a[4]) + bf2f(b[4]) + acc[4] * inv;
        r1.y = i1.y + bf2f(a[5]) + bf2f(b[5]) + acc[5] * inv;
        r1.z = i1.z + bf2f(a[6]) + bf2f(b[6]) + acc[6] * inv;
        r1.w = i1.w + bf2f(a[7]) + bf2f(b[7]) + acc[7] * inv;
        *(f4*)(out + ro)     = r0;
        *(f4*)(out + ro + 4) = r1;
    }
}

extern "C" void kernel_launch(void* const* d_in, const int* in_sizes, int n_in,
                              void* d_out, int out_size, void* d_ws, size_t ws_size,
                              hipStream_t stream) {
    const float* user_emb = (const float*)d_in[0];
    const float* item_emb = (const float*)d_in[1];
    const int*   uidx     = (const int*)d_in[2];
    const int*   iidx     = (const int*)d_in[3];

    float* out      = (float*)d_out;
    float* out_item = out;                           // [N_ITEMS, 64]
    float* out_user = out + (size_t)N_ITEMS * EMB;   // [N_USERS, 64]

    // workspace layout
    u16* ws16    = (u16*)d_ws;
    u16* ua_bf   = ws16;                                   // user agg hop0
    u16* ub_bf   = ua_bf + (size_t)N_USERS * EMB;          // user agg hop1
    u16* ia_bf   = ub_bf + (size_t)N_USERS * EMB;          // item agg hop0
    u16* ib_bf   = ia_bf + (size_t)N_ITEMS * EMB;          // item agg hop1
    u16* uemb_bf = ib_bf + (size_t)N_ITEMS * EMB;
    u16* iemb_bf = uemb_bf + (size_t)N_USERS * EMB;
    int* rec     = (int*)(iemb_bf + (size_t)N_ITEMS * EMB);
    int* list    = rec + 2 * N_EDGES;
    int* H       = list + 2 * N_EDGES + 16;   // +16 pad: staged list tail reads
    int* HB      = H + HN;
    int* part    = HB + HN;
    int2* desc   = (int2*)(part + HTILES + 1);  // 8B aligned region

    // bf16 copies of the embeddings (hop-0 gather sources)
    conv_kernel<<<(NROWS * EMB / 4 + 255) / 256, 256, 0, stream>>>(user_emb, uemb_bf, item_emb, iemb_bf);

    // bucketed CSR build (+ in-bucket degree-sorted packed descriptors)
    histA_kernel<<<B1, 256, 0, stream>>>(uidx, iidx, H);
    hscan_tile_kernel<<<HTILES, 256, 0, stream>>>(H, part);
    hscan_write_kernel<<<HTILES, 256, 0, stream>>>(H, part, HB);
    scatterA_kernel<<<B1, 256, 0, stream>>>(uidx, iidx, HB, rec);
    bucketB_kernel<<<2 * NBUK, 256, 0, stream>>>(HB, rec, list, desc);

    // 3 hops: hop0 emb->agg0, hop1 agg0->agg1, hop2 agg1->out (fused final)
    const int gblocks = 4688;   // ceil(ceil(NROWS/8)*64 / 256), = 8*586 exactly

    gather_norm_v5<<<gblocks, 256, 0, stream>>>(
        iemb_bf, uemb_bf, list, desc,
        ua_bf, ia_bf, nullptr, nullptr, nullptr, nullptr,
        nullptr, nullptr, nullptr, nullptr, 0);

    gather_norm_v5<<<gblocks, 256, 0, stream>>>(
        ia_bf, ua_bf, list, desc,
        ub_bf, ib_bf, nullptr, nullptr, nullptr, nullptr,
        nullptr, nullptr, nullptr, nullptr, 0);

    gather_norm_v5<<<gblocks, 256, 0, stream>>>(
        ib_bf, ub_bf, list, desc,
        nullptr, nullptr, ua_bf, ia_bf, ub_bf, ib_bf,
        out_user, out_item, user_emb, item_emb, 1);
}